// Round 1
// baseline (73.159 us; speedup 1.0000x reference)
//
#include <hip/hip_runtime.h>
#include <hip/hip_bf16.h>

// Problem shapes (fixed by reference):
//   codes: [32, 512, 64, 64] f32   (256 MB)
//   sem:   [32, 8, 256, 256] i32   (nearest-downsample -> sem[b,s,4h,4w])
//   out:   [32, 8*512] f32 (as [bs, s*c, 1, 1]); out[b*4096 + s*512 + c]

#define BS   32
#define CS   512
#define SEG  8
#define HS   64
#define WS   64
#define HW   (HS*WS)          // 4096
#define SEMH 256
#define SEMW 256

// ---------------------------------------------------------------------------
// Kernel A: build packed segment-mask byte per downsampled pixel + areas.
// grid = BS blocks, 256 threads. Each thread handles 16 pixels.
// ---------------------------------------------------------------------------
__global__ __launch_bounds__(256) void mask_area_kernel(
    const int* __restrict__ sem,
    unsigned char* __restrict__ mask8,   // [BS][HW]
    float* __restrict__ area)            // [BS][SEG]
{
    const int b = blockIdx.x;
    const int t = threadIdx.x;

    int cnt[SEG];
#pragma unroll
    for (int s = 0; s < SEG; ++s) cnt[s] = 0;

    const int* semb = sem + (size_t)b * SEG * SEMH * SEMW;

#pragma unroll
    for (int i = 0; i < 16; ++i) {
        const int hw = i * 256 + t;          // 0..4095
        const int h  = hw >> 6;              // /64
        const int w  = hw & 63;
        const int* p = semb + (h * 4) * SEMW + (w * 4);
        unsigned int m = 0;
#pragma unroll
        for (int s = 0; s < SEG; ++s) {
            if (p[s * (SEMH * SEMW)] != 0) { m |= (1u << s); cnt[s]++; }
        }
        mask8[b * HW + hw] = (unsigned char)m;
    }

    // block reduce counts
#pragma unroll
    for (int off = 32; off; off >>= 1)
#pragma unroll
        for (int s = 0; s < SEG; ++s) cnt[s] += __shfl_down(cnt[s], off);

    __shared__ int redc[4][SEG];
    const int lane = t & 63, wv = t >> 6;
    if (lane == 0) {
#pragma unroll
        for (int s = 0; s < SEG; ++s) redc[wv][s] = cnt[s];
    }
    __syncthreads();
    if (t < SEG) {
        area[b * SEG + t] = (float)(redc[0][t] + redc[1][t] + redc[2][t] + redc[3][t]);
    }
}

// ---------------------------------------------------------------------------
// Kernel B: per (b,c) block — stream 4096 floats, masked accumulate 8 segment
// sums + 1 global sum, block reduce, write the 8 outputs.
// grid = BS*CS blocks, 256 threads.
// ---------------------------------------------------------------------------
__global__ __launch_bounds__(256) void seg_mean_kernel(
    const float* __restrict__ codes,
    const unsigned char* __restrict__ mask8,
    const float* __restrict__ area,
    float* __restrict__ out)
{
    const int bc = blockIdx.x;
    const int b  = bc >> 9;     // /CS
    const int c  = bc & 511;
    const int t  = threadIdx.x;

    const float* src = codes + (size_t)bc * HW;
    const unsigned char* mb = mask8 + b * HW;

    float acc[SEG + 1];
#pragma unroll
    for (int s = 0; s <= SEG; ++s) acc[s] = 0.0f;

#pragma unroll
    for (int i = 0; i < 4; ++i) {
        const int hw = i * 1024 + t * 4;
        const float4 v = *reinterpret_cast<const float4*>(src + hw);
        const unsigned int m4 = *reinterpret_cast<const unsigned int*>(mb + hw);
        const float vals[4] = { v.x, v.y, v.z, v.w };
#pragma unroll
        for (int p = 0; p < 4; ++p) {
            const float val = vals[p];
            const unsigned int m = m4 >> (8 * p);
            acc[SEG] += val;
#pragma unroll
            for (int s = 0; s < SEG; ++s)
                acc[s] += (m & (1u << s)) ? val : 0.0f;
        }
    }

    // wave reduce (64-wide), then 4-wave LDS reduce
#pragma unroll
    for (int off = 32; off; off >>= 1)
#pragma unroll
        for (int s = 0; s <= SEG; ++s) acc[s] += __shfl_down(acc[s], off);

    __shared__ float red[4][SEG + 1];
    const int lane = t & 63, wv = t >> 6;
    if (lane == 0) {
#pragma unroll
        for (int s = 0; s <= SEG; ++s) red[wv][s] = acc[s];
    }
    __syncthreads();

    if (t < SEG) {
        const float seg  = red[0][t] + red[1][t] + red[2][t] + red[3][t];
        const float glob = red[0][SEG] + red[1][SEG] + red[2][SEG] + red[3][SEG];
        const float a    = area[b * SEG + t];
        out[b * (SEG * CS) + t * CS + c] = (a > 0.0f) ? (seg / a)
                                                      : (glob * (1.0f / (float)HW));
    }
}

// ---------------------------------------------------------------------------
extern "C" void kernel_launch(void* const* d_in, const int* in_sizes, int n_in,
                              void* d_out, int out_size, void* d_ws, size_t ws_size,
                              hipStream_t stream) {
    const float* codes = (const float*)d_in[0];
    const int*   sem   = (const int*)d_in[1];
    float*       out   = (float*)d_out;

    unsigned char* mask8 = (unsigned char*)d_ws;                  // BS*HW bytes
    float*         area  = (float*)((char*)d_ws + BS * HW);       // BS*SEG floats

    mask_area_kernel<<<BS, 256, 0, stream>>>(sem, mask8, area);
    seg_mean_kernel<<<BS * CS, 256, 0, stream>>>(codes, mask8, area, out);
}

// Round 2
// 61.407 us; speedup vs baseline: 1.1914x; 1.1914x over previous
//
#include <hip/hip_runtime.h>
#include <hip/hip_bf16.h>

// Problem shapes (fixed by reference):
//   codes: [32, 512, 64, 64] f32   (256 MB)
//   sem:   [32, 8, 256, 256] i32   (nearest-downsample -> sem[b,s,4h,4w])
//   out:   [32, 8*512] f32 (as [bs, s*c, 1, 1]); out[b*4096 + s*512 + c]

#define BS    32
#define CS    512
#define SEG   8
#define HS    64
#define WS    64
#define HW    (HS*WS)          // 4096
#define SEMH  256
#define SEMW  256
#define NCHUNK 16              // kernel A chunks per batch (256 px each)
#define CPB   2                // kernel B channels per block

// ---------------------------------------------------------------------------
// Kernel A: packed segment-mask byte per downsampled pixel + partial counts.
// grid = BS*NCHUNK = 512 blocks, 256 threads, 1 pixel/thread.
// ---------------------------------------------------------------------------
__global__ __launch_bounds__(256) void mask_area_kernel(
    const int* __restrict__ sem,
    unsigned char* __restrict__ mask8,   // [BS][HW]
    int* __restrict__ partial)           // [BS][NCHUNK][SEG]
{
    const int blk   = blockIdx.x;
    const int b     = blk >> 4;
    const int chunk = blk & (NCHUNK - 1);
    const int t     = threadIdx.x;

    const int hw = chunk * 256 + t;      // 0..4095
    const int h  = hw >> 6;
    const int w  = hw & 63;
    const int* p = sem + (size_t)b * SEG * SEMH * SEMW + (h * 4) * SEMW + (w * 4);

    unsigned int m = 0;
#pragma unroll
    for (int s = 0; s < SEG; ++s)
        if (p[s * (SEMH * SEMW)] != 0) m |= (1u << s);
    mask8[b * HW + hw] = (unsigned char)m;

    // per-wave population counts via ballot, then 4-wave LDS combine
    __shared__ int redc[4][SEG];
    const int lane = t & 63, wv = t >> 6;
#pragma unroll
    for (int s = 0; s < SEG; ++s) {
        unsigned long long bal = __ballot((m >> s) & 1u);
        if (lane == 0) redc[wv][s] = __popcll(bal);
    }
    __syncthreads();
    if (t < SEG)
        partial[(b * NCHUNK + chunk) * SEG + t] =
            redc[0][t] + redc[1][t] + redc[2][t] + redc[3][t];
}

// ---------------------------------------------------------------------------
// Kernel B: per (b, c0..c0+1) block — stream 2*4096 floats, masked accumulate
// 8 segment sums + 1 global sum per channel, block reduce, write outputs.
// grid = BS*CS/CPB = 8192 blocks, 256 threads.
// ---------------------------------------------------------------------------
__global__ __launch_bounds__(256) void seg_mean_kernel(
    const float* __restrict__ codes,
    const unsigned char* __restrict__ mask8,
    const int* __restrict__ partial,
    float* __restrict__ out)
{
    const int blk = blockIdx.x;
    const int b   = blk >> 8;                 // / (CS/CPB)
    const int c0  = (blk & 255) * CPB;
    const int t   = threadIdx.x;

    const float* src = codes + ((size_t)b * CS + c0) * HW;
    const unsigned char* mb = mask8 + b * HW;

    float acc[CPB][SEG + 1];
#pragma unroll
    for (int cc = 0; cc < CPB; ++cc)
#pragma unroll
        for (int s = 0; s <= SEG; ++s) acc[cc][s] = 0.0f;

#pragma unroll
    for (int i = 0; i < 4; ++i) {
        const int hw = i * 1024 + t * 4;
        const unsigned int m4 = *reinterpret_cast<const unsigned int*>(mb + hw);
#pragma unroll
        for (int cc = 0; cc < CPB; ++cc) {
            const float4 v = *reinterpret_cast<const float4*>(src + cc * HW + hw);
            const float vals[4] = { v.x, v.y, v.z, v.w };
#pragma unroll
            for (int p = 0; p < 4; ++p) {
                const float val = vals[p];
                const unsigned int m = m4 >> (8 * p);
                acc[cc][SEG] += val;
#pragma unroll
                for (int s = 0; s < SEG; ++s)
                    acc[cc][s] += (m & (1u << s)) ? val : 0.0f;
            }
        }
    }

    // wave reduce (64-wide), then 4-wave LDS reduce
#pragma unroll
    for (int off = 32; off; off >>= 1)
#pragma unroll
        for (int cc = 0; cc < CPB; ++cc)
#pragma unroll
            for (int s = 0; s <= SEG; ++s)
                acc[cc][s] += __shfl_down(acc[cc][s], off);

    __shared__ float red[4][CPB][SEG + 1];
    const int lane = t & 63, wv = t >> 6;
    if (lane == 0) {
#pragma unroll
        for (int cc = 0; cc < CPB; ++cc)
#pragma unroll
            for (int s = 0; s <= SEG; ++s) red[wv][cc][s] = acc[cc][s];
    }
    __syncthreads();

    if (t < SEG) {
        int ai = 0;
#pragma unroll
        for (int k = 0; k < NCHUNK; ++k)
            ai += partial[(b * NCHUNK + k) * SEG + t];
        const float a = (float)ai;
#pragma unroll
        for (int cc = 0; cc < CPB; ++cc) {
            const float seg  = red[0][cc][t]   + red[1][cc][t]   + red[2][cc][t]   + red[3][cc][t];
            const float glob = red[0][cc][SEG] + red[1][cc][SEG] + red[2][cc][SEG] + red[3][cc][SEG];
            out[b * (SEG * CS) + t * CS + (c0 + cc)] =
                (a > 0.0f) ? (seg / a) : (glob * (1.0f / (float)HW));
        }
    }
}

// ---------------------------------------------------------------------------
extern "C" void kernel_launch(void* const* d_in, const int* in_sizes, int n_in,
                              void* d_out, int out_size, void* d_ws, size_t ws_size,
                              hipStream_t stream) {
    const float* codes = (const float*)d_in[0];
    const int*   sem   = (const int*)d_in[1];
    float*       out   = (float*)d_out;

    unsigned char* mask8   = (unsigned char*)d_ws;                 // BS*HW bytes
    int*           partial = (int*)((char*)d_ws + BS * HW);        // BS*NCHUNK*SEG ints

    mask_area_kernel<<<BS * NCHUNK, 256, 0, stream>>>(sem, mask8, partial);
    seg_mean_kernel<<<BS * CS / CPB, 256, 0, stream>>>(codes, mask8, partial, out);
}

// Round 3
// 57.394 us; speedup vs baseline: 1.2747x; 1.0699x over previous
//
#include <hip/hip_runtime.h>
#include <hip/hip_bf16.h>

// Problem shapes (fixed by reference):
//   codes: [32, 512, 64, 64] f32   (256 MB)
//   sem:   [32, 8, 256, 256] i32   (nearest-downsample -> sem[b,s,4h,4w])
//   out:   [32, 8*512] f32 (as [bs, s*c, 1, 1]); out[b*4096 + s*512 + c]

#define BS    32
#define CS    512
#define SEG   8
#define HS    64
#define WS    64
#define HW    (HS*WS)          // 4096
#define SEMH  256
#define SEMW  256
#define NCHUNK 16              // kernel A chunks per batch (256 px each)
#define CPB   2                // kernel B channels per block

// ---------------------------------------------------------------------------
// Kernel A: packed segment-mask byte per downsampled pixel + partial counts.
// grid = BS*NCHUNK = 512 blocks, 256 threads, 1 pixel/thread.
// ---------------------------------------------------------------------------
__global__ __launch_bounds__(256) void mask_area_kernel(
    const int* __restrict__ sem,
    unsigned char* __restrict__ mask8,   // [BS][HW]
    int* __restrict__ partial)           // [BS][NCHUNK][SEG]
{
    const int blk   = blockIdx.x;
    const int b     = blk >> 4;
    const int chunk = blk & (NCHUNK - 1);
    const int t     = threadIdx.x;

    const int hw = chunk * 256 + t;      // 0..4095
    const int h  = hw >> 6;
    const int w  = hw & 63;
    const int* p = sem + (size_t)b * SEG * SEMH * SEMW + (h * 4) * SEMW + (w * 4);

    unsigned int m = 0;
#pragma unroll
    for (int s = 0; s < SEG; ++s)
        if (p[s * (SEMH * SEMW)] != 0) m |= (1u << s);
    mask8[b * HW + hw] = (unsigned char)m;

    // per-wave population counts via ballot, then 4-wave LDS combine
    __shared__ int redc[4][SEG];
    const int lane = t & 63, wv = t >> 6;
#pragma unroll
    for (int s = 0; s < SEG; ++s) {
        unsigned long long bal = __ballot((m >> s) & 1u);
        if (lane == 0) redc[wv][s] = __popcll(bal);
    }
    __syncthreads();
    if (t < SEG)
        partial[(b * NCHUNK + chunk) * SEG + t] =
            redc[0][t] + redc[1][t] + redc[2][t] + redc[3][t];
}

// ---------------------------------------------------------------------------
// Kernel B: one wave per (b, 2-channel group). Each lane streams 64 px/channel
// via float4 loads; mask bits spread to byte weights (mul24 trick) so each
// segment accumulate is v_cvt_f32_ubyteN + v_fmac (2 ops). Butterfly reduce,
// lanes 0..7 write the 2 outputs for their segment.
// grid = BS*CS/CPB = 8192 blocks, 64 threads.
// ---------------------------------------------------------------------------
__global__ __launch_bounds__(64) void seg_mean_kernel(
    const float* __restrict__ codes,
    const unsigned char* __restrict__ mask8,
    const int* __restrict__ partial,
    float* __restrict__ out)
{
    const int blk = blockIdx.x;
    const int b   = blk >> 8;                 // / (CS/CPB)
    const int c0  = (blk & 255) * CPB;
    const int l   = threadIdx.x;              // 0..63

    const float* src = codes + ((size_t)b * CS + c0) * HW;
    const unsigned char* mb = mask8 + b * HW;

    float acc[CPB][SEG];
    float gl[CPB];
#pragma unroll
    for (int cc = 0; cc < CPB; ++cc) {
        gl[cc] = 0.0f;
#pragma unroll
        for (int s = 0; s < SEG; ++s) acc[cc][s] = 0.0f;
    }

#pragma unroll
    for (int i = 0; i < 16; ++i) {
        const int hw = i * 256 + l * 4;
        const unsigned int m4 = *reinterpret_cast<const unsigned int*>(mb + hw);
        const float4 v0 = *reinterpret_cast<const float4*>(src + hw);
        const float4 v1 = *reinterpret_cast<const float4*>(src + HW + hw);
        const float va[CPB][4] = { { v0.x, v0.y, v0.z, v0.w },
                                   { v1.x, v1.y, v1.z, v1.w } };
#pragma unroll
        for (int p = 0; p < 4; ++p) {
            // spread 8 mask bits of pixel p into 8 bytes (0/1 each)
            const unsigned int lo = (m4 >> (8 * p)) & 0xFu;
            const unsigned int hi = (m4 >> (8 * p + 4)) & 0xFu;
            const unsigned int slo = ((unsigned int)__mul24((int)lo, 0x00204081)) & 0x01010101u;
            const unsigned int shi = ((unsigned int)__mul24((int)hi, 0x00204081)) & 0x01010101u;
            float w[SEG];
            w[0] = (float)( slo        & 0xffu);   // v_cvt_f32_ubyte0
            w[1] = (float)((slo >> 8)  & 0xffu);   // v_cvt_f32_ubyte1
            w[2] = (float)((slo >> 16) & 0xffu);   // v_cvt_f32_ubyte2
            w[3] = (float)( slo >> 24        );    // v_cvt_f32_ubyte3
            w[4] = (float)( shi        & 0xffu);
            w[5] = (float)((shi >> 8)  & 0xffu);
            w[6] = (float)((shi >> 16) & 0xffu);
            w[7] = (float)( shi >> 24        );
#pragma unroll
            for (int cc = 0; cc < CPB; ++cc) {
                const float val = va[cc][p];
                gl[cc] += val;
#pragma unroll
                for (int s = 0; s < SEG; ++s)
                    acc[cc][s] = fmaf(val, w[s], acc[cc][s]);
            }
        }
    }

    // butterfly reduce across the wave — every lane ends with the totals
#pragma unroll
    for (int off = 32; off; off >>= 1) {
#pragma unroll
        for (int cc = 0; cc < CPB; ++cc) {
            gl[cc] += __shfl_xor(gl[cc], off);
#pragma unroll
            for (int s = 0; s < SEG; ++s)
                acc[cc][s] += __shfl_xor(acc[cc][s], off);
        }
    }

    if (l < SEG) {
        int ai = 0;
#pragma unroll
        for (int k = 0; k < NCHUNK; ++k)
            ai += partial[(b * NCHUNK + k) * SEG + l];
        const float a = (float)ai;
#pragma unroll
        for (int cc = 0; cc < CPB; ++cc) {
            // static-index select of acc[cc][l] (avoid runtime reg indexing)
            float seg = 0.0f;
#pragma unroll
            for (int s = 0; s < SEG; ++s)
                seg = (l == s) ? acc[cc][s] : seg;
            out[b * (SEG * CS) + l * CS + (c0 + cc)] =
                (a > 0.0f) ? (seg / a) : (gl[cc] * (1.0f / (float)HW));
        }
    }
}

// ---------------------------------------------------------------------------
extern "C" void kernel_launch(void* const* d_in, const int* in_sizes, int n_in,
                              void* d_out, int out_size, void* d_ws, size_t ws_size,
                              hipStream_t stream) {
    const float* codes = (const float*)d_in[0];
    const int*   sem   = (const int*)d_in[1];
    float*       out   = (float*)d_out;

    unsigned char* mask8   = (unsigned char*)d_ws;                 // BS*HW bytes
    int*           partial = (int*)((char*)d_ws + BS * HW);        // BS*NCHUNK*SEG ints

    mask_area_kernel<<<BS * NCHUNK, 256, 0, stream>>>(sem, mask8, partial);
    seg_mean_kernel<<<BS * CS / CPB, 64, 0, stream>>>(codes, mask8, partial, out);
}